// Round 9
// baseline (31.337 us; speedup 1.0000x reference)
//
#include <hip/hip_runtime.h>

// VQ-VAE quantizer forward — R19: 16 waves/CU (2 x 512-thr blocks co-resident).
//   inputs  [B=8, C=64, T=16, H=32, W=32] fp32   (layout: b*C*THW + c*THW + r)
//   codebook[K=512, C=64] fp32
// outputs: q_z [B,C,T,H,W] fp32, vq_loss, commitment_loss (concat flat)
//
// dist(p,k) = ||e_k||^2 - 2*x_p.e_k. MFMA C-init = ||e||^2 => acc IS the
// distance. 9-bit code packed into mantissa LSBs => argmin is pure f32 min.
// Loss via ||e-x||^2 = ||x||^2 + d_best.
//
// Occupancy history: R11 (512thr x 1blk/CU) and R12 (256thr x 2blk/CU) BOTH
// run 8 waves/CU — occ ~15% in every measured variant; body latency-bound.
// R18 removed the per-block build (prep kernel writes the exact LDS image;
// main DMAs it via global_load_lds) but stayed at 8 waves/CU: total neutral.
// R19 single change vs R18: 256 blocks x 512 thr. 2 blocks/CU co-resident
// (2 x 69.6 KB LDS = 139 <= 160 KB; VGPR ~88 => 4 waves/SIMD) = 16 waves/CU,
// 2x every prior config. One block's x-drain/NT-store burst hides under the
// other's scan. No launch-bounds cap (R14 spill trap), no fences (R15), no
// register prefetch (R13b/R16).

#define K_CODES 512
#define NCH     64
#define THW     16384
#define NELEM   8388608
#define NBLK    256
#define IMG_BYTES 67584                    // 65536 cb + 2048 norms
#define PART_OFF  (IMG_BYTES / 4)          // float offset of partials in ws

typedef __attribute__((ext_vector_type(8))) short bf16x8;
typedef __attribute__((ext_vector_type(4))) float f32x4;

__device__ __forceinline__ unsigned short f32_bf16(float f) {
    unsigned u = __float_as_uint(f);
    u += 0x7FFFu + ((u >> 16) & 1u);          // round-to-nearest-even
    return (unsigned short)(u >> 16);
}

// Build the LDS image: byte r*128 + ((j8^(r&7))*16) = bf16(-2*cb[r][j8*8..+8)),
// byte 65536 + r*4 = ||e_r||^2 (fp32). Same layout the in-block build made.
__global__ void vq_prep(const float* __restrict__ cb,
                        unsigned char* __restrict__ pbuf) {
    const int t = blockIdx.x * 256 + threadIdx.x;
    if (t < 4096) {                       // 512 rows x 8 chunks
        const int r  = t >> 3;
        const int j8 = t & 7;
        const f32x4* cr = (const f32x4*)(cb + r * NCH + j8 * 8);
        const f32x4 e0 = cr[0];
        const f32x4 e1 = cr[1];
        bf16x8 pk;
        pk[0] = (short)f32_bf16(-2.f * e0[0]);
        pk[1] = (short)f32_bf16(-2.f * e0[1]);
        pk[2] = (short)f32_bf16(-2.f * e0[2]);
        pk[3] = (short)f32_bf16(-2.f * e0[3]);
        pk[4] = (short)f32_bf16(-2.f * e1[0]);
        pk[5] = (short)f32_bf16(-2.f * e1[1]);
        pk[6] = (short)f32_bf16(-2.f * e1[2]);
        pk[7] = (short)f32_bf16(-2.f * e1[3]);
        *(bf16x8*)(pbuf + r * 128 + ((j8 ^ (r & 7)) * 16)) = pk;
    } else if (t < 4608) {                // 512 norms
        const int r = t - 4096;
        const f32x4* cr = (const f32x4*)(cb + r * NCH);
        float s = 0.f;
        #pragma unroll
        for (int jj = 0; jj < 16; ++jj) {
            const f32x4 e = cr[jj];
            s = fmaf(e[0], e[0], s);
            s = fmaf(e[1], e[1], s);
            s = fmaf(e[2], e[2], s);
            s = fmaf(e[3], e[3], s);
        }
        *(float*)(pbuf + 65536 + r * 4) = s;
    }
}

__global__ __launch_bounds__(512) void vq_main(
        const float* __restrict__ x,
        const float* __restrict__ cb,
        const unsigned char* __restrict__ pbuf,
        float* __restrict__ out,
        float* __restrict__ partials) {
    __shared__ __align__(16) unsigned char lds_img[IMG_BYTES];
    __shared__ int lds_idx[512];

    const int tid  = threadIdx.x;
    const int lane = tid & 63;
    const int w    = tid >> 6;       // wave 0..7
    const int g    = lane >> 4;      // 16-lane group 0..3
    const int r15  = lane & 15;

    const int blk  = blockIdx.x;
    const int b    = blk >> 5;                 // batch (32 blocks per batch)
    const int rblk = (blk & 31) << 9;          // 512 positions per block
    const int rw   = rblk + w * 64;            // wave's first position
    const float* xb = x + (size_t)b * (NCH * THW);

    // ---- DMA the prepacked image into LDS: 8 waves x (8 cb rounds + 1 norm).
    // global_load_lds: per-lane global src, wave-uniform LDS base + lane*16.
    // Layout linear (swizzle pre-applied in pbuf). Zero VALU. ----
    {
        const int lbase = w * 1024 + lane * 16;
        #pragma unroll
        for (int r = 0; r < 8; ++r) {
            __builtin_amdgcn_global_load_lds(
                (__attribute__((address_space(1))) const void*)(pbuf + r * 8192 + lbase),
                (__attribute__((address_space(3))) void*)(lds_img + r * 8192 + w * 1024),
                16, 0, 0);
        }
        // norms: 2048B = 8 waves x 256B (size 4)
        __builtin_amdgcn_global_load_lds(
            (__attribute__((address_space(1))) const void*)(pbuf + 65536 + w * 256 + lane * 4),
            (__attribute__((address_space(3))) void*)(lds_img + 65536 + w * 256),
            4, 0, 0);
    }

    // ---- x loads: f32x4; 16 lanes x 16B = 256B contiguous (overlap DMA) ----
    // lane(g,r15) gets positions {rw+4*r15+tt, tt=0..3} of channel kf*32+g*8+j
    f32x4 xv[2][8];
    #pragma unroll
    for (int kf = 0; kf < 2; ++kf)
        #pragma unroll
        for (int j = 0; j < 8; ++j)
            xv[kf][j] = *(const f32x4*)(xb + (size_t)(kf * 32 + g * 8 + j) * THW
                                           + rw + 4 * r15);

    // ---- convert x to bf16 A-frags + fp32 ||x||^2 partial ----
    bf16x8 af[4][2];
    float  xn = 0.f;
    #pragma unroll
    for (int kf = 0; kf < 2; ++kf)
        #pragma unroll
        for (int j = 0; j < 8; ++j) {
            const f32x4 v = xv[kf][j];
            xn = fmaf(v[0], v[0], xn);
            xn = fmaf(v[1], v[1], xn);
            xn = fmaf(v[2], v[2], xn);
            xn = fmaf(v[3], v[3], xn);
            af[0][kf][j] = (short)f32_bf16(v[0]);
            af[1][kf][j] = (short)f32_bf16(v[1]);
            af[2][kf][j] = (short)f32_bf16(v[2]);
            af[3][kf][j] = (short)f32_bf16(v[3]);
        }

    __syncthreads();   // drains DMA (vmcnt) — codebook + norms resident

    // ---- scan all 512 codes (R12/R15-proven body) ----
    float best[4][4];
    #pragma unroll
    for (int tt = 0; tt < 4; ++tt)
        #pragma unroll
        for (int i = 0; i < 4; ++i) best[tt][i] = 3.4e38f;

    const int swz = (r15 & 7) << 4;
    const unsigned char* pb0 = lds_img + r15 * 128 + ((g * 16) ^ swz);
    const unsigned char* pb1 = lds_img + r15 * 128 + ((64 + g * 16) ^ swz);
    const float* lds_norm = (const float*)(lds_img + 65536);
    #pragma unroll
    for (int f = 0; f < 32; ++f) {
        const bf16x8 b0 = *(const bf16x8*)(pb0 + f * 2048);
        const bf16x8 b1 = *(const bf16x8*)(pb1 + f * 2048);
        const float nrm = lds_norm[f * 16 + r15];
        const unsigned code = (unsigned)(f * 16 + r15);   // lane's B-column
        #pragma unroll
        for (int tt = 0; tt < 4; ++tt) {
            f32x4 acc = {nrm, nrm, nrm, nrm};
            acc = __builtin_amdgcn_mfma_f32_16x16x32_bf16(af[tt][0], b0, acc, 0, 0, 0);
            acc = __builtin_amdgcn_mfma_f32_16x16x32_bf16(af[tt][1], b1, acc, 0, 0, 0);
            #pragma unroll
            for (int i = 0; i < 4; ++i) {   // acc[i]: pos rw+4*(4g+i)+tt
                const float pkv = __uint_as_float(
                    (__float_as_uint(acc[i]) & ~511u) | code);
                best[tt][i] = fminf(best[tt][i], pkv);
            }
        }
    }

    // ---- wave-local argmin (reduce over r15 = code axis) ----
    float sd = 0.f;
    int   idxs[4][4];
    #pragma unroll
    for (int tt = 0; tt < 4; ++tt) {
        #pragma unroll
        for (int i = 0; i < 4; ++i) {
            float v = best[tt][i];
            #pragma unroll
            for (int off = 8; off; off >>= 1) v = fminf(v, __shfl_xor(v, off));
            sd += v;                                // replicated x16 per group
            idxs[tt][i] = (int)(__float_as_uint(v) & 511u);
        }
    }
    if (r15 == 0) {                   // same-wave RAW only (no barrier needed)
        #pragma unroll
        for (int tt = 0; tt < 4; ++tt)
            #pragma unroll
            for (int i = 0; i < 4; ++i)
                lds_idx[w * 64 + 16 * g + 4 * i + tt] = idxs[tt][i];
    }
    // per-wave loss partial: sum(||x||^2) + sum(d_best)/16
    float part = fmaf(sd, 0.0625f, xn);
    #pragma unroll
    for (int off = 32; off; off >>= 1) part += __shfl_down(part, off);
    if (lane == 0) partials[blk * 8 + w] = part;

    // ---- epilogue: lane = one position; q from fp32 cb (L2-hot); NT stores
    const int bc = lds_idx[tid];                       // tid == w*64 + lane
    float* oq = out + (size_t)b * (NCH * THW) + (rblk + tid);
    const f32x4* crow = (const f32x4*)(cb + (size_t)bc * NCH);
    #pragma unroll
    for (int jj = 0; jj < 16; ++jj) {
        const f32x4 e = crow[jj];
        const size_t c0 = (size_t)(jj * 4) * THW;
        __builtin_nontemporal_store(e[0], oq + c0);
        __builtin_nontemporal_store(e[1], oq + c0 + THW);
        __builtin_nontemporal_store(e[2], oq + c0 + 2 * THW);
        __builtin_nontemporal_store(e[3], oq + c0 + 3 * THW);
    }
}

__global__ void vq_finalize(const float* __restrict__ partials,
                            float* __restrict__ out) {
    const int tid = threadIdx.x;   // 256 threads, 2048 partials, fixed order
    float v = 0.f;
    #pragma unroll
    for (int k = 0; k < 8; ++k) v += partials[tid + 256 * k];
    #pragma unroll
    for (int off = 32; off; off >>= 1) v += __shfl_down(v, off);
    __shared__ float ws[4];
    if ((tid & 63) == 0) ws[tid >> 6] = v;
    __syncthreads();
    if (tid == 0) {
        const float total  = (ws[0] + ws[1]) + (ws[2] + ws[3]);
        const float commit = total * (1.0f / (float)NELEM);
        out[NELEM]     = 0.25f * commit;   // vq_loss
        out[NELEM + 1] = commit;           // commitment_loss
    }
}

extern "C" void kernel_launch(void* const* d_in, const int* in_sizes, int n_in,
                              void* d_out, int out_size, void* d_ws, size_t ws_size,
                              hipStream_t stream) {
    const float* x  = (const float*)d_in[0];
    const float* cb = (const float*)d_in[1];
    float* out      = (float*)d_out;
    unsigned char* pbuf = (unsigned char*)d_ws;    // 67,584 B LDS image
    float* partials = (float*)d_ws + PART_OFF;     // 2048 floats after image

    vq_prep<<<18, 256, 0, stream>>>(cb, pbuf);
    vq_main<<<NBLK, 512, 0, stream>>>(x, cb, pbuf, out, partials);
    vq_finalize<<<1, 256, 0, stream>>>(partials, out);
}